// Round 3
// baseline (534.333 us; speedup 1.0000x reference)
//
#include <hip/hip_runtime.h>

// ConceptEmbedding: out = 0.1*e_free + 0.9*centroid[argmin d2]
// e_free = (seq @ emb) / rowsum(seq);  seq [8192 x 8192] f32, emb [8192 x 256] f32
// Strategy: split-precision bf16 MFMA (hi/lo, 3 passes) ~= f32 accuracy.
//   K0: pack emb and (cent-0.5) into MFMA-fragment-ordered bf16 hi/lo; f64 cnorm.
//   K1: BM=64 x BN=256, split-K=8 (1024 WGs -> 4 blocks/CU = 32 waves/CU), 8 waves,
//       wave tile 64x32 (no B duplication), LDS double-buffer (1 barrier/step),
//       A f32->LDS split w/ XOR swizzle, B frags direct-from-global (L2-resident).
//   K2: reduce 8 partials -> e_free; mean-shifted MFMA vs centroids; f64 argmin; blend.

typedef unsigned short u16;
typedef unsigned int   u32;
using bf16x8 = __attribute__((ext_vector_type(8))) short;
using f32x4  = __attribute__((ext_vector_type(4))) float;

#define MFMA_B16(A,B,C) __builtin_amdgcn_mfma_f32_16x16x32_bf16((A),(B),(C),0,0,0)

#define NSPLIT 8

static __device__ __forceinline__ u16 f2bf(float f){
  u32 u = __builtin_bit_cast(u32, f);
  u += 0x7FFFu + ((u >> 16) & 1u);   // RNE
  return (u16)(u >> 16);
}
static __device__ __forceinline__ float bf2f(u16 h){
  u32 u = ((u32)h) << 16;
  return __builtin_bit_cast(float, u);
}
static __device__ __forceinline__ void split2(float va, float vb, u32& hw, u32& lw){
  u16 ha = f2bf(va), hb = f2bf(vb);
  hw = (u32)ha | ((u32)hb << 16);
  lw = (u32)f2bf(va - bf2f(ha)) | ((u32)f2bf(vb - bf2f(hb)) << 16);
}

// ---------------- ws layout (bytes) ----------------
#define SZ_PART    ((size_t)NSPLIT*8192UL*256UL*4UL)   // 67,108,864  f32 partials [8][8192][256]
#define OFF_CNT    (SZ_PART)
#define SZ_CNT     ((size_t)NSPLIT*8192UL*4UL)         // cnt partials [8][8192]
#define OFF_BHI    (OFF_CNT + SZ_CNT)
#define SZ_BHI     (8192UL*256UL*2UL)                  // 4 MB
#define OFF_BLO    (OFF_BHI + SZ_BHI)
#define OFF_CTHI   (OFF_BLO + SZ_BHI)
#define SZ_CT      (512UL*256UL*2UL)                   // 256 KB
#define OFF_CTLO   (OFF_CTHI + SZ_CT)
#define OFF_CNORM  (OFF_CTLO + SZ_CT)                  // 512 doubles

// ---------------- K0: pack B/CT fragments, cnorm ----------------
__global__ __launch_bounds__(256) void ce_prep(
    const float* __restrict__ emb, const float* __restrict__ cent,
    u16* __restrict__ Bhi, u16* __restrict__ Blo,
    u16* __restrict__ CThi, u16* __restrict__ CTlo,
    double* __restrict__ cnormd)
{
  const int b = blockIdx.x, t = threadIdx.x;
  const int l = t & 63;
  const int lr = l & 15, lk = l >> 4;
  if (b < 1024) {                      // emb frag (nt 0..15, ksg 0..255): elem j = emb[ksg*32+lk*8+j][nt*16+lr]
    const int g  = b * 4 + (t >> 6);
    const int nt = g >> 8, ksg = g & 255;
    u32 hw[4], lw[4];
    #pragma unroll
    for (int p = 0; p < 4; ++p) {
      float va = emb[(size_t)(ksg*32 + lk*8 + 2*p    )*256 + nt*16 + lr];
      float vb = emb[(size_t)(ksg*32 + lk*8 + 2*p + 1)*256 + nt*16 + lr];
      split2(va, vb, hw[p], lw[p]);
    }
    const size_t fi = ((size_t)nt*256 + ksg)*64 + l;
    *(uint4*)(Bhi + fi*8) = make_uint4(hw[0],hw[1],hw[2],hw[3]);
    *(uint4*)(Blo + fi*8) = make_uint4(lw[0],lw[1],lw[2],lw[3]);
  } else if (b < 1088) {               // cent^T frags (nt 0..31, ksg 0..7), shifted by -0.5
    const int g  = (b - 1024) * 4 + (t >> 6);
    const int nt = g >> 3, ksg = g & 7;
    u32 hw[4], lw[4];
    #pragma unroll
    for (int p = 0; p < 4; ++p) {
      float va = cent[(size_t)(nt*16 + lr)*256 + ksg*32 + lk*8 + 2*p    ] - 0.5f;
      float vb = cent[(size_t)(nt*16 + lr)*256 + ksg*32 + lk*8 + 2*p + 1] - 0.5f;
      split2(va, vb, hw[p], lw[p]);
    }
    const size_t fi = ((size_t)nt*8 + ksg)*64 + l;
    *(uint4*)(CThi + fi*8) = make_uint4(hw[0],hw[1],hw[2],hw[3]);
    *(uint4*)(CTlo + fi*8) = make_uint4(lw[0],lw[1],lw[2],lw[3]);
  } else {                             // cnorm: |cent_k - 0.5|^2 in f64
    const int row = (b - 1088)*8 + (t >> 5);
    const int h = t & 31;
    double s = 0.0;
    #pragma unroll
    for (int j = 0; j < 8; ++j) {
      float x = cent[(size_t)row*256 + h*8 + j] - 0.5f;
      s += (double)x * (double)x;
    }
    #pragma unroll
    for (int off = 16; off > 0; off >>= 1) s += __shfl_xor(s, off);
    if (h == 0) cnormd[row] = s;
  }
}

// ---------------- K1: main split-bf16 GEMM, 1024 WGs x 512 thr ----------------
// blk: mt = blk>>3 (row tile of 64), ks = blk&7 (K-eighth of 1024)
__global__ __launch_bounds__(512, 8) void ce_gemm(
    const float* __restrict__ seq,
    const u16* __restrict__ Bhi, const u16* __restrict__ Blo,
    float* __restrict__ part, float* __restrict__ cntpart)
{
  __shared__ char Ah[2][64*128];      // 64 rows x 64 bf16 (128B), slot-swizzled, dbuf
  __shared__ char Al[2][64*128];
  __shared__ float cred[64][8];

  const int t   = threadIdx.x;
  const int blk = blockIdx.x;
  const int mt  = blk >> 3;
  const int ks  = blk & 7;
  const size_t rowBase = (size_t)mt * 64;
  const int ar  = t >> 3;             // staging row 0..63 (fixed per thread -> count accum)
  const int ac  = t & 7;              // 8-float chunk
  const float* aptr = seq + (rowBase + ar) * 8192 + (size_t)ks * 1024 + ac * 8;

  const int w = t >> 6, l = t & 63;   // wave w owns cols w*32 .. w*32+31 (no B dup)
  const int lr = l & 15, lk = l >> 4;

  f32x4 acc[4][2];
  #pragma unroll
  for (int i = 0; i < 4; ++i)
    #pragma unroll
    for (int j = 0; j < 2; ++j) acc[i][j] = (f32x4){0.f,0.f,0.f,0.f};

  float csum = 0.f;
  float4 areg0, areg1;
  areg0 = *(const float4*)(aptr);
  areg1 = *(const float4*)(aptr + 4);

  // prologue: stage tile 0 into buf0, start loading tile 1
  {
    float v[8] = {areg0.x, areg0.y, areg0.z, areg0.w, areg1.x, areg1.y, areg1.z, areg1.w};
    #pragma unroll
    for (int i = 0; i < 8; ++i) csum += v[i];
    u32 hw[4], lw[4];
    #pragma unroll
    for (int p = 0; p < 4; ++p) split2(v[2*p], v[2*p+1], hw[p], lw[p]);
    const int off = ar*128 + ((ac ^ (ar & 7)) << 4);
    *(uint4*)(Ah[0] + off) = make_uint4(hw[0],hw[1],hw[2],hw[3]);
    *(uint4*)(Al[0] + off) = make_uint4(lw[0],lw[1],lw[2],lw[3]);
  }
  aptr += 64;
  areg0 = *(const float4*)(aptr);
  areg1 = *(const float4*)(aptr + 4);
  __syncthreads();

  for (int step = 0; step < 16; ++step) {
    const int cur = step & 1;
    // B frag loads for this step (global, L2-resident; issued early)
    const int ksg0 = ks*32 + step*2;
    bf16x8 bh[2][2], bl[2][2];
    #pragma unroll
    for (int ksub = 0; ksub < 2; ++ksub)
      #pragma unroll
      for (int ni = 0; ni < 2; ++ni) {
        const size_t fi = (((size_t)(w*2 + ni))*256 + (ksg0 + ksub))*64 + l;
        bh[ksub][ni] = *(const bf16x8*)(Bhi + fi*8);
        bl[ksub][ni] = *(const bf16x8*)(Blo + fi*8);
      }
    // stage NEXT tile into buf^1 (prev step's reads of that buf finished before last barrier)
    if (step < 15) {
      float v[8] = {areg0.x, areg0.y, areg0.z, areg0.w, areg1.x, areg1.y, areg1.z, areg1.w};
      #pragma unroll
      for (int i = 0; i < 8; ++i) csum += v[i];
      u32 hw[4], lw[4];
      #pragma unroll
      for (int p = 0; p < 4; ++p) split2(v[2*p], v[2*p+1], hw[p], lw[p]);
      const int off = ar*128 + ((ac ^ (ar & 7)) << 4);
      *(uint4*)(Ah[cur^1] + off) = make_uint4(hw[0],hw[1],hw[2],hw[3]);
      *(uint4*)(Al[cur^1] + off) = make_uint4(lw[0],lw[1],lw[2],lw[3]);
      if (step < 14) {
        aptr += 64;
        areg0 = *(const float4*)(aptr);
        areg1 = *(const float4*)(aptr + 4);
      }
    }
    // A frags from buf[cur] + MFMA
    #pragma unroll
    for (int ksub = 0; ksub < 2; ++ksub) {
      bf16x8 ah[4], alo[4];
      #pragma unroll
      for (int mi = 0; mi < 4; ++mi) {
        const int row = mi*16 + lr;
        const int off = row*128 + (((ksub*4 + lk) ^ (row & 7)) << 4);
        ah[mi]  = *(const bf16x8*)(Ah[cur] + off);
        alo[mi] = *(const bf16x8*)(Al[cur] + off);
      }
      #pragma unroll
      for (int mi = 0; mi < 4; ++mi)
        #pragma unroll
        for (int ni = 0; ni < 2; ++ni) {
          acc[mi][ni] = MFMA_B16(ah[mi],  bh[ksub][ni], acc[mi][ni]);
          acc[mi][ni] = MFMA_B16(alo[mi], bh[ksub][ni], acc[mi][ni]);
          acc[mi][ni] = MFMA_B16(ah[mi],  bl[ksub][ni], acc[mi][ni]);
        }
    }
    __syncthreads();
  }
  // count partials
  cred[ar][ac] = csum;
  __syncthreads();
  if (t < 64) {
    float c = 0.f;
    #pragma unroll
    for (int j = 0; j < 8; ++j) c += cred[t][j];
    cntpart[(size_t)ks*8192 + rowBase + t] = c;
  }
  // partial e_free store (C/D layout: col = l&15, row = (l>>4)*4 + reg)
  float* pbase = part + ((size_t)ks*8192 + rowBase)*256;
  #pragma unroll
  for (int mi = 0; mi < 4; ++mi)
    #pragma unroll
    for (int ni = 0; ni < 2; ++ni) {
      const int col = w*32 + ni*16 + lr;
      #pragma unroll
      for (int rr = 0; rr < 4; ++rr) {
        const int row = mi*16 + lk*4 + rr;
        pbase[(size_t)row*256 + col] = acc[mi][ni][rr];
      }
    }
}

// ---------------- K2: reduce + centroid argmin + blend, 256 WGs x 256 thr ----------------
__global__ __launch_bounds__(256) void ce_cent(
    const float* __restrict__ part, const float* __restrict__ cntpart,
    const u16* __restrict__ CThi, const u16* __restrict__ CTlo,
    const double* __restrict__ cnormd, const float* __restrict__ cent,
    float* __restrict__ out)
{
  __shared__ float eL[32][256];       // e_free rows (f32)
  __shared__ char Eh[32*512];         // shifted e hi bf16, swizzled [row][256]
  __shared__ char El[32*512];
  __shared__ float GL[32][512];       // (e-.5)·(c-.5)^T
  __shared__ float cntL[32];
  __shared__ float enred[32][8];
  __shared__ float enL[32];

  const int t = threadIdx.x;
  const size_t rb = (size_t)blockIdx.x * 32;
  const int r  = t >> 3;
  const int c0 = (t & 7) * 32;

  if (t < 32) {
    float s = 0.f;
    #pragma unroll
    for (int p = 0; p < NSPLIT; ++p) s += cntpart[(size_t)p*8192 + rb + t];
    cntL[t] = (s == 0.f) ? 1.f : s;
  }
  __syncthreads();
  const float inv = 1.0f / cntL[r];
  float en = 0.f;
  #pragma unroll
  for (int jp = 0; jp < 4; ++jp) {    // 8 cols per iter
    float e8[8];
    #pragma unroll
    for (int q = 0; q < 2; ++q) {
      const float* p0 = part + (rb + r)*256 + c0 + jp*8 + q*4;
      float4 e4 = {0.f, 0.f, 0.f, 0.f};
      #pragma unroll
      for (int p = 0; p < NSPLIT; ++p) {
        float4 s0 = *(const float4*)(p0 + (size_t)p*2097152);
        e4.x += s0.x; e4.y += s0.y; e4.z += s0.z; e4.w += s0.w;
      }
      e4.x *= inv; e4.y *= inv; e4.z *= inv; e4.w *= inv;
      *(float4*)&eL[r][c0 + jp*8 + q*4] = e4;
      e8[q*4+0] = e4.x; e8[q*4+1] = e4.y; e8[q*4+2] = e4.z; e8[q*4+3] = e4.w;
    }
    u32 hw[4], lw[4];
    #pragma unroll
    for (int p = 0; p < 4; ++p) {
      float va = e8[2*p] - 0.5f, vb = e8[2*p+1] - 0.5f;
      split2(va, vb, hw[p], lw[p]);
      en += va*va + vb*vb;
    }
    const int slot = (t & 7)*4 + jp;                 // 0..31
    const int off  = r*512 + ((slot ^ (r & 7)) << 4);
    *(uint4*)(Eh + off) = make_uint4(hw[0],hw[1],hw[2],hw[3]);
    *(uint4*)(El + off) = make_uint4(lw[0],lw[1],lw[2],lw[3]);
  }
  enred[r][t & 7] = en;
  __syncthreads();
  if (t < 32) {
    float s = 0.f;
    #pragma unroll
    for (int j = 0; j < 8; ++j) s += enred[t][j];
    enL[t] = s;
  }
  // G = Ẽ · C̃^T via 3-pass split MFMA; wave w owns 128 centroids
  const int w = t >> 6, l = t & 63, lr = l & 15, lk = l >> 4;
  f32x4 acc[2][8];
  #pragma unroll
  for (int i = 0; i < 2; ++i)
    #pragma unroll
    for (int j = 0; j < 8; ++j) acc[i][j] = (f32x4){0.f,0.f,0.f,0.f};
  #pragma unroll
  for (int ksub = 0; ksub < 8; ++ksub) {
    bf16x8 ah[2], alo[2];
    #pragma unroll
    for (int mi = 0; mi < 2; ++mi) {
      const int row = mi*16 + lr;
      const int off = row*512 + (((ksub*4 + lk) ^ (row & 7)) << 4);
      ah[mi]  = *(const bf16x8*)(Eh + off);
      alo[mi] = *(const bf16x8*)(El + off);
    }
    bf16x8 bh[8], bl[8];
    #pragma unroll
    for (int ni = 0; ni < 8; ++ni) {
      const size_t fi = (((size_t)(w*8 + ni))*8 + ksub)*64 + l;
      bh[ni] = *(const bf16x8*)(CThi + fi*8);
      bl[ni] = *(const bf16x8*)(CTlo + fi*8);
    }
    #pragma unroll
    for (int mi = 0; mi < 2; ++mi)
      #pragma unroll
      for (int ni = 0; ni < 8; ++ni) {
        acc[mi][ni] = MFMA_B16(ah[mi],  bh[ni], acc[mi][ni]);
        acc[mi][ni] = MFMA_B16(alo[mi], bh[ni], acc[mi][ni]);
        acc[mi][ni] = MFMA_B16(ah[mi],  bl[ni], acc[mi][ni]);
      }
  }
  #pragma unroll
  for (int mi = 0; mi < 2; ++mi)
    #pragma unroll
    for (int ni = 0; ni < 8; ++ni)
      #pragma unroll
      for (int rr = 0; rr < 4; ++rr)
        GL[mi*16 + lk*4 + rr][w*128 + ni*16 + lr] = acc[mi][ni][rr];
  __syncthreads();
  // argmin (f64 combine; exact first-index tie-break) + blend + store; wave w rows w*8..w*8+7
  for (int i = 0; i < 8; ++i) {
    const int row = w*8 + i;
    const double en_ = (double)enL[row];
    double best = 1e300; int bk = 0;
    #pragma unroll
    for (int jj = 0; jj < 8; ++jj) {
      const int k = jj*64 + l;
      const double d2 = en_ + cnormd[k] - 2.0*(double)GL[row][k];
      if (d2 < best) { best = d2; bk = k; }
    }
    #pragma unroll
    for (int off = 32; off > 0; off >>= 1) {
      const double ov = __shfl_xor(best, off);
      const int   ok = __shfl_xor(bk, off);
      if (ov < best || (ov == best && ok < bk)) { best = ov; bk = ok; }
    }
    const float* crow = cent + (size_t)bk*256;
    float4 ef = *(const float4*)&eL[row][l*4];
    float4 cf = *(const float4*)(crow + l*4);
    float4 o;
    o.x = 0.1f*ef.x + 0.9f*cf.x;
    o.y = 0.1f*ef.y + 0.9f*cf.y;
    o.z = 0.1f*ef.z + 0.9f*cf.z;
    o.w = 0.1f*ef.w + 0.9f*cf.w;
    *(float4*)(out + (rb + row)*256 + l*4) = o;
  }
}

extern "C" void kernel_launch(void* const* d_in, const int* in_sizes, int n_in,
                              void* d_out, int out_size, void* d_ws, size_t ws_size,
                              hipStream_t stream) {
  const float* seq  = (const float*)d_in[0];
  const float* emb  = (const float*)d_in[1];
  const float* cent = (const float*)d_in[2];
  float* out = (float*)d_out;
  char* ws = (char*)d_ws;

  float*  part    = (float*) (ws);
  float*  cntpart = (float*) (ws + OFF_CNT);
  u16*    Bhi     = (u16*)   (ws + OFF_BHI);
  u16*    Blo     = (u16*)   (ws + OFF_BLO);
  u16*    CThi    = (u16*)   (ws + OFF_CTHI);
  u16*    CTlo    = (u16*)   (ws + OFF_CTLO);
  double* cnormd  = (double*)(ws + OFF_CNORM);

  hipLaunchKernelGGL(ce_prep, dim3(1152), dim3(256), 0, stream,
                     emb, cent, Bhi, Blo, CThi, CTlo, cnormd);
  hipLaunchKernelGGL(ce_gemm, dim3(1024), dim3(512), 0, stream,
                     seq, Bhi, Blo, part, cntpart);
  hipLaunchKernelGGL(ce_cent, dim3(256), dim3(256), 0, stream,
                     part, cntpart, CThi, CTlo, cnormd, cent, out);
}

// Round 4
// 183.331 us; speedup vs baseline: 2.9146x; 2.9146x over previous
//
#include <hip/hip_runtime.h>

// ConceptEmbedding: out = 0.1*e_free + 0.9*centroid[argmin d2]
// e_free = (seq @ emb) / rowsum(seq);  seq [8192 x 8192] f32, emb [8192 x 256] f32
// Strategy: split-precision bf16 MFMA (hi/lo, 3 passes) ~= f32 accuracy.
//   K0: pack emb and (cent-0.5) into MFMA-fragment-ordered bf16 hi/lo; f64 cnorm.
//   K1: BM=64 x BN=256, split-K=8 (1024 WGs -> 4 blocks/CU = 32 waves/CU), 8 waves,
//       wave tile 64x32 (no B duplication), LDS double-buffer (1 barrier/step),
//       A f32->LDS split w/ XOR swizzle, B frags direct-from-global (L2-resident).
//       launch_bounds(512,4): VGPR cap 128 (R3's (512,8) forced VGPR=32 -> spills).
//   K2: reduce 8 partials -> e_free; mean-shifted MFMA vs centroids; f64 argmin; blend.

typedef unsigned short u16;
typedef unsigned int   u32;
using bf16x8 = __attribute__((ext_vector_type(8))) short;
using f32x4  = __attribute__((ext_vector_type(4))) float;

#define MFMA_B16(A,B,C) __builtin_amdgcn_mfma_f32_16x16x32_bf16((A),(B),(C),0,0,0)

#define NSPLIT 8

static __device__ __forceinline__ u16 f2bf(float f){
  u32 u = __builtin_bit_cast(u32, f);
  u += 0x7FFFu + ((u >> 16) & 1u);   // RNE
  return (u16)(u >> 16);
}
static __device__ __forceinline__ float bf2f(u16 h){
  u32 u = ((u32)h) << 16;
  return __builtin_bit_cast(float, u);
}
static __device__ __forceinline__ void split2(float va, float vb, u32& hw, u32& lw){
  u16 ha = f2bf(va), hb = f2bf(vb);
  hw = (u32)ha | ((u32)hb << 16);
  lw = (u32)f2bf(va - bf2f(ha)) | ((u32)f2bf(vb - bf2f(hb)) << 16);
}

// ---------------- ws layout (bytes) ----------------
#define SZ_PART    ((size_t)NSPLIT*8192UL*256UL*4UL)   // 67,108,864  f32 partials [8][8192][256]
#define OFF_CNT    (SZ_PART)
#define SZ_CNT     ((size_t)NSPLIT*8192UL*4UL)         // cnt partials [8][8192]
#define OFF_BHI    (OFF_CNT + SZ_CNT)
#define SZ_BHI     (8192UL*256UL*2UL)                  // 4 MB
#define OFF_BLO    (OFF_BHI + SZ_BHI)
#define OFF_CTHI   (OFF_BLO + SZ_BHI)
#define SZ_CT      (512UL*256UL*2UL)                   // 256 KB
#define OFF_CTLO   (OFF_CTHI + SZ_CT)
#define OFF_CNORM  (OFF_CTLO + SZ_CT)                  // 512 doubles

// ---------------- K0: pack B/CT fragments, cnorm ----------------
__global__ __launch_bounds__(256) void ce_prep(
    const float* __restrict__ emb, const float* __restrict__ cent,
    u16* __restrict__ Bhi, u16* __restrict__ Blo,
    u16* __restrict__ CThi, u16* __restrict__ CTlo,
    double* __restrict__ cnormd)
{
  const int b = blockIdx.x, t = threadIdx.x;
  const int l = t & 63;
  const int lr = l & 15, lk = l >> 4;
  if (b < 1024) {                      // emb frag (nt 0..15, ksg 0..255): elem j = emb[ksg*32+lk*8+j][nt*16+lr]
    const int g  = b * 4 + (t >> 6);
    const int nt = g >> 8, ksg = g & 255;
    u32 hw[4], lw[4];
    #pragma unroll
    for (int p = 0; p < 4; ++p) {
      float va = emb[(size_t)(ksg*32 + lk*8 + 2*p    )*256 + nt*16 + lr];
      float vb = emb[(size_t)(ksg*32 + lk*8 + 2*p + 1)*256 + nt*16 + lr];
      split2(va, vb, hw[p], lw[p]);
    }
    const size_t fi = ((size_t)nt*256 + ksg)*64 + l;
    *(uint4*)(Bhi + fi*8) = make_uint4(hw[0],hw[1],hw[2],hw[3]);
    *(uint4*)(Blo + fi*8) = make_uint4(lw[0],lw[1],lw[2],lw[3]);
  } else if (b < 1088) {               // cent^T frags (nt 0..31, ksg 0..7), shifted by -0.5
    const int g  = (b - 1024) * 4 + (t >> 6);
    const int nt = g >> 3, ksg = g & 7;
    u32 hw[4], lw[4];
    #pragma unroll
    for (int p = 0; p < 4; ++p) {
      float va = cent[(size_t)(nt*16 + lr)*256 + ksg*32 + lk*8 + 2*p    ] - 0.5f;
      float vb = cent[(size_t)(nt*16 + lr)*256 + ksg*32 + lk*8 + 2*p + 1] - 0.5f;
      split2(va, vb, hw[p], lw[p]);
    }
    const size_t fi = ((size_t)nt*8 + ksg)*64 + l;
    *(uint4*)(CThi + fi*8) = make_uint4(hw[0],hw[1],hw[2],hw[3]);
    *(uint4*)(CTlo + fi*8) = make_uint4(lw[0],lw[1],lw[2],lw[3]);
  } else {                             // cnorm: |cent_k - 0.5|^2 in f64
    const int row = (b - 1088)*8 + (t >> 5);
    const int h = t & 31;
    double s = 0.0;
    #pragma unroll
    for (int j = 0; j < 8; ++j) {
      float x = cent[(size_t)row*256 + h*8 + j] - 0.5f;
      s += (double)x * (double)x;
    }
    #pragma unroll
    for (int off = 16; off > 0; off >>= 1) s += __shfl_xor(s, off);
    if (h == 0) cnormd[row] = s;
  }
}

// ---------------- K1: main split-bf16 GEMM, 1024 WGs x 512 thr ----------------
// blk: mt = blk>>3 (row tile of 64), ks = blk&7 (K-eighth of 1024)
__global__ __launch_bounds__(512, 4) void ce_gemm(
    const float* __restrict__ seq,
    const u16* __restrict__ Bhi, const u16* __restrict__ Blo,
    float* __restrict__ part, float* __restrict__ cntpart)
{
  __shared__ char Ah[2][64*128];      // 64 rows x 64 bf16 (128B), slot-swizzled, dbuf
  __shared__ char Al[2][64*128];
  __shared__ float cred[64][8];

  const int t   = threadIdx.x;
  const int blk = blockIdx.x;
  const int mt  = blk >> 3;
  const int ks  = blk & 7;
  const size_t rowBase = (size_t)mt * 64;
  const int ar  = t >> 3;             // staging row 0..63 (fixed per thread -> count accum)
  const int ac  = t & 7;              // 8-float chunk
  const float* aptr = seq + (rowBase + ar) * 8192 + (size_t)ks * 1024 + ac * 8;

  const int w = t >> 6, l = t & 63;   // wave w owns cols w*32 .. w*32+31 (no B dup)
  const int lr = l & 15, lk = l >> 4;

  f32x4 acc[4][2];
  #pragma unroll
  for (int i = 0; i < 4; ++i)
    #pragma unroll
    for (int j = 0; j < 2; ++j) acc[i][j] = (f32x4){0.f,0.f,0.f,0.f};

  float csum = 0.f;
  float4 areg0, areg1;
  areg0 = *(const float4*)(aptr);
  areg1 = *(const float4*)(aptr + 4);

  // prologue: stage tile 0 into buf0, start loading tile 1
  {
    float v[8] = {areg0.x, areg0.y, areg0.z, areg0.w, areg1.x, areg1.y, areg1.z, areg1.w};
    #pragma unroll
    for (int i = 0; i < 8; ++i) csum += v[i];
    u32 hw[4], lw[4];
    #pragma unroll
    for (int p = 0; p < 4; ++p) split2(v[2*p], v[2*p+1], hw[p], lw[p]);
    const int off = ar*128 + ((ac ^ (ar & 7)) << 4);
    *(uint4*)(Ah[0] + off) = make_uint4(hw[0],hw[1],hw[2],hw[3]);
    *(uint4*)(Al[0] + off) = make_uint4(lw[0],lw[1],lw[2],lw[3]);
  }
  aptr += 64;
  areg0 = *(const float4*)(aptr);
  areg1 = *(const float4*)(aptr + 4);
  __syncthreads();

  for (int step = 0; step < 16; ++step) {
    const int cur = step & 1;
    // B frag loads for this step (global, L2-resident; issued early)
    const int ksg0 = ks*32 + step*2;
    bf16x8 bh[2][2], bl[2][2];
    #pragma unroll
    for (int ksub = 0; ksub < 2; ++ksub)
      #pragma unroll
      for (int ni = 0; ni < 2; ++ni) {
        const size_t fi = (((size_t)(w*2 + ni))*256 + (ksg0 + ksub))*64 + l;
        bh[ksub][ni] = *(const bf16x8*)(Bhi + fi*8);
        bl[ksub][ni] = *(const bf16x8*)(Blo + fi*8);
      }
    // stage NEXT tile into buf^1 (prev step's reads of that buf finished before last barrier)
    if (step < 15) {
      float v[8] = {areg0.x, areg0.y, areg0.z, areg0.w, areg1.x, areg1.y, areg1.z, areg1.w};
      #pragma unroll
      for (int i = 0; i < 8; ++i) csum += v[i];
      u32 hw[4], lw[4];
      #pragma unroll
      for (int p = 0; p < 4; ++p) split2(v[2*p], v[2*p+1], hw[p], lw[p]);
      const int off = ar*128 + ((ac ^ (ar & 7)) << 4);
      *(uint4*)(Ah[cur^1] + off) = make_uint4(hw[0],hw[1],hw[2],hw[3]);
      *(uint4*)(Al[cur^1] + off) = make_uint4(lw[0],lw[1],lw[2],lw[3]);
      if (step < 14) {
        aptr += 64;
        areg0 = *(const float4*)(aptr);
        areg1 = *(const float4*)(aptr + 4);
      }
    }
    // A frags from buf[cur] + MFMA
    #pragma unroll
    for (int ksub = 0; ksub < 2; ++ksub) {
      bf16x8 ah[4], alo[4];
      #pragma unroll
      for (int mi = 0; mi < 4; ++mi) {
        const int row = mi*16 + lr;
        const int off = row*128 + (((ksub*4 + lk) ^ (row & 7)) << 4);
        ah[mi]  = *(const bf16x8*)(Ah[cur] + off);
        alo[mi] = *(const bf16x8*)(Al[cur] + off);
      }
      #pragma unroll
      for (int mi = 0; mi < 4; ++mi)
        #pragma unroll
        for (int ni = 0; ni < 2; ++ni) {
          acc[mi][ni] = MFMA_B16(ah[mi],  bh[ksub][ni], acc[mi][ni]);
          acc[mi][ni] = MFMA_B16(alo[mi], bh[ksub][ni], acc[mi][ni]);
          acc[mi][ni] = MFMA_B16(ah[mi],  bl[ksub][ni], acc[mi][ni]);
        }
    }
    __syncthreads();
  }
  // count partials
  cred[ar][ac] = csum;
  __syncthreads();
  if (t < 64) {
    float c = 0.f;
    #pragma unroll
    for (int j = 0; j < 8; ++j) c += cred[t][j];
    cntpart[(size_t)ks*8192 + rowBase + t] = c;
  }
  // partial e_free store (C/D layout: col = l&15, row = (l>>4)*4 + reg)
  float* pbase = part + ((size_t)ks*8192 + rowBase)*256;
  #pragma unroll
  for (int mi = 0; mi < 4; ++mi)
    #pragma unroll
    for (int ni = 0; ni < 2; ++ni) {
      const int col = w*32 + ni*16 + lr;
      #pragma unroll
      for (int rr = 0; rr < 4; ++rr) {
        const int row = mi*16 + lk*4 + rr;
        pbase[(size_t)row*256 + col] = acc[mi][ni][rr];
      }
    }
}

// ---------------- K2: reduce + centroid argmin + blend, 256 WGs x 256 thr ----------------
__global__ __launch_bounds__(256) void ce_cent(
    const float* __restrict__ part, const float* __restrict__ cntpart,
    const u16* __restrict__ CThi, const u16* __restrict__ CTlo,
    const double* __restrict__ cnormd, const float* __restrict__ cent,
    float* __restrict__ out)
{
  __shared__ float eL[32][256];       // e_free rows (f32)
  __shared__ char Eh[32*512];         // shifted e hi bf16, swizzled [row][256]
  __shared__ char El[32*512];
  __shared__ float GL[32][512];       // (e-.5)·(c-.5)^T
  __shared__ float cntL[32];
  __shared__ float enred[32][8];
  __shared__ float enL[32];

  const int t = threadIdx.x;
  const size_t rb = (size_t)blockIdx.x * 32;
  const int r  = t >> 3;
  const int c0 = (t & 7) * 32;

  if (t < 32) {
    float s = 0.f;
    #pragma unroll
    for (int p = 0; p < NSPLIT; ++p) s += cntpart[(size_t)p*8192 + rb + t];
    cntL[t] = (s == 0.f) ? 1.f : s;
  }
  __syncthreads();
  const float inv = 1.0f / cntL[r];
  float en = 0.f;
  #pragma unroll
  for (int jp = 0; jp < 4; ++jp) {    // 8 cols per iter
    float e8[8];
    #pragma unroll
    for (int q = 0; q < 2; ++q) {
      const float* p0 = part + (rb + r)*256 + c0 + jp*8 + q*4;
      float4 e4 = {0.f, 0.f, 0.f, 0.f};
      #pragma unroll
      for (int p = 0; p < NSPLIT; ++p) {
        float4 s0 = *(const float4*)(p0 + (size_t)p*2097152);
        e4.x += s0.x; e4.y += s0.y; e4.z += s0.z; e4.w += s0.w;
      }
      e4.x *= inv; e4.y *= inv; e4.z *= inv; e4.w *= inv;
      *(float4*)&eL[r][c0 + jp*8 + q*4] = e4;
      e8[q*4+0] = e4.x; e8[q*4+1] = e4.y; e8[q*4+2] = e4.z; e8[q*4+3] = e4.w;
    }
    u32 hw[4], lw[4];
    #pragma unroll
    for (int p = 0; p < 4; ++p) {
      float va = e8[2*p] - 0.5f, vb = e8[2*p+1] - 0.5f;
      split2(va, vb, hw[p], lw[p]);
      en += va*va + vb*vb;
    }
    const int slot = (t & 7)*4 + jp;                 // 0..31
    const int off  = r*512 + ((slot ^ (r & 7)) << 4);
    *(uint4*)(Eh + off) = make_uint4(hw[0],hw[1],hw[2],hw[3]);
    *(uint4*)(El + off) = make_uint4(lw[0],lw[1],lw[2],lw[3]);
  }
  enred[r][t & 7] = en;
  __syncthreads();
  if (t < 32) {
    float s = 0.f;
    #pragma unroll
    for (int j = 0; j < 8; ++j) s += enred[t][j];
    enL[t] = s;
  }
  // G = Ẽ · C̃^T via 3-pass split MFMA; wave w owns 128 centroids
  const int w = t >> 6, l = t & 63, lr = l & 15, lk = l >> 4;
  f32x4 acc[2][8];
  #pragma unroll
  for (int i = 0; i < 2; ++i)
    #pragma unroll
    for (int j = 0; j < 8; ++j) acc[i][j] = (f32x4){0.f,0.f,0.f,0.f};
  #pragma unroll
  for (int ksub = 0; ksub < 8; ++ksub) {
    bf16x8 ah[2], alo[2];
    #pragma unroll
    for (int mi = 0; mi < 2; ++mi) {
      const int row = mi*16 + lr;
      const int off = row*512 + (((ksub*4 + lk) ^ (row & 7)) << 4);
      ah[mi]  = *(const bf16x8*)(Eh + off);
      alo[mi] = *(const bf16x8*)(El + off);
    }
    bf16x8 bh[8], bl[8];
    #pragma unroll
    for (int ni = 0; ni < 8; ++ni) {
      const size_t fi = (((size_t)(w*8 + ni))*8 + ksub)*64 + l;
      bh[ni] = *(const bf16x8*)(CThi + fi*8);
      bl[ni] = *(const bf16x8*)(CTlo + fi*8);
    }
    #pragma unroll
    for (int mi = 0; mi < 2; ++mi)
      #pragma unroll
      for (int ni = 0; ni < 8; ++ni) {
        acc[mi][ni] = MFMA_B16(ah[mi],  bh[ni], acc[mi][ni]);
        acc[mi][ni] = MFMA_B16(alo[mi], bh[ni], acc[mi][ni]);
        acc[mi][ni] = MFMA_B16(ah[mi],  bl[ni], acc[mi][ni]);
      }
  }
  #pragma unroll
  for (int mi = 0; mi < 2; ++mi)
    #pragma unroll
    for (int ni = 0; ni < 8; ++ni)
      #pragma unroll
      for (int rr = 0; rr < 4; ++rr)
        GL[mi*16 + lk*4 + rr][w*128 + ni*16 + lr] = acc[mi][ni][rr];
  __syncthreads();
  // argmin (f64 combine; exact first-index tie-break) + blend + store; wave w rows w*8..w*8+7
  for (int i = 0; i < 8; ++i) {
    const int row = w*8 + i;
    const double en_ = (double)enL[row];
    double best = 1e300; int bk = 0;
    #pragma unroll
    for (int jj = 0; jj < 8; ++jj) {
      const int k = jj*64 + l;
      const double d2 = en_ + cnormd[k] - 2.0*(double)GL[row][k];
      if (d2 < best) { best = d2; bk = k; }
    }
    #pragma unroll
    for (int off = 32; off > 0; off >>= 1) {
      const double ov = __shfl_xor(best, off);
      const int   ok = __shfl_xor(bk, off);
      if (ov < best || (ov == best && ok < bk)) { best = ov; bk = ok; }
    }
    const float* crow = cent + (size_t)bk*256;
    float4 ef = *(const float4*)&eL[row][l*4];
    float4 cf = *(const float4*)(crow + l*4);
    float4 o;
    o.x = 0.1f*ef.x + 0.9f*cf.x;
    o.y = 0.1f*ef.y + 0.9f*cf.y;
    o.z = 0.1f*ef.z + 0.9f*cf.z;
    o.w = 0.1f*ef.w + 0.9f*cf.w;
    *(float4*)(out + (rb + row)*256 + l*4) = o;
  }
}

extern "C" void kernel_launch(void* const* d_in, const int* in_sizes, int n_in,
                              void* d_out, int out_size, void* d_ws, size_t ws_size,
                              hipStream_t stream) {
  const float* seq  = (const float*)d_in[0];
  const float* emb  = (const float*)d_in[1];
  const float* cent = (const float*)d_in[2];
  float* out = (float*)d_out;
  char* ws = (char*)d_ws;

  float*  part    = (float*) (ws);
  float*  cntpart = (float*) (ws + OFF_CNT);
  u16*    Bhi     = (u16*)   (ws + OFF_BHI);
  u16*    Blo     = (u16*)   (ws + OFF_BLO);
  u16*    CThi    = (u16*)   (ws + OFF_CTHI);
  u16*    CTlo    = (u16*)   (ws + OFF_CTLO);
  double* cnormd  = (double*)(ws + OFF_CNORM);

  hipLaunchKernelGGL(ce_prep, dim3(1152), dim3(256), 0, stream,
                     emb, cent, Bhi, Blo, CThi, CTlo, cnormd);
  hipLaunchKernelGGL(ce_gemm, dim3(1024), dim3(512), 0, stream,
                     seq, Bhi, Blo, part, cntpart);
  hipLaunchKernelGGL(ce_cent, dim3(256), dim3(256), 0, stream,
                     part, cntpart, CThi, CTlo, cnormd, cent, out);
}

// Round 5
// 142.555 us; speedup vs baseline: 3.7483x; 1.2860x over previous
//
#include <hip/hip_runtime.h>

// ConceptEmbedding: out = 0.1*e_free + 0.9*centroid[argmin d2]
// e_free = (seq @ emb) / rowsum(seq);  seq [8192 x 8192] f32, emb [8192 x 256] f32
// Strategy: split-precision bf16 MFMA (hi/lo, 3 passes) ~= f32 accuracy.
//   K0: pack emb and (cent-0.5) into MFMA-fragment-ordered bf16 hi/lo; f64 cnorm.
//   K1: BM=64 x BN=256, split-K=4 (512 WGs, 2 blocks/CU — reg-file capped: 32 AGPR acc
//       + ~64 arch VGPR ~= 96 total -> 16 waves/CU max), 8 waves, wave tile 64x32.
//       ILP fix: B frags software-pipelined in registers (ksub0 prefetched 1 step
//       ahead under prev MFMA burst; ksub1 issued at step start, used after 24 MFMAs).
//       A f32->LDS split w/ XOR swizzle, LDS dbuf, 1 barrier/step. cnt via shfl.
//   K2: reduce 4 partials -> e_free; mean-shifted MFMA vs centroids; f64 argmin; blend.

typedef unsigned short u16;
typedef unsigned int   u32;
using bf16x8 = __attribute__((ext_vector_type(8))) short;
using f32x4  = __attribute__((ext_vector_type(4))) float;

#define MFMA_B16(A,B,C) __builtin_amdgcn_mfma_f32_16x16x32_bf16((A),(B),(C),0,0,0)

#define NSPLIT 4

static __device__ __forceinline__ u16 f2bf(float f){
  u32 u = __builtin_bit_cast(u32, f);
  u += 0x7FFFu + ((u >> 16) & 1u);   // RNE
  return (u16)(u >> 16);
}
static __device__ __forceinline__ float bf2f(u16 h){
  u32 u = ((u32)h) << 16;
  return __builtin_bit_cast(float, u);
}
static __device__ __forceinline__ void split2(float va, float vb, u32& hw, u32& lw){
  u16 ha = f2bf(va), hb = f2bf(vb);
  hw = (u32)ha | ((u32)hb << 16);
  lw = (u32)f2bf(va - bf2f(ha)) | ((u32)f2bf(vb - bf2f(hb)) << 16);
}

// ---------------- ws layout (bytes) ----------------
#define SZ_PART    ((size_t)NSPLIT*8192UL*256UL*4UL)   // 33,554,432  f32 partials [4][8192][256]
#define OFF_CNT    (SZ_PART)
#define SZ_CNT     ((size_t)NSPLIT*8192UL*4UL)
#define OFF_BHI    (OFF_CNT + SZ_CNT)
#define SZ_BHI     (8192UL*256UL*2UL)                  // 4 MB
#define OFF_BLO    (OFF_BHI + SZ_BHI)
#define OFF_CTHI   (OFF_BLO + SZ_BHI)
#define SZ_CT      (512UL*256UL*2UL)                   // 256 KB
#define OFF_CTLO   (OFF_CTHI + SZ_CT)
#define OFF_CNORM  (OFF_CTLO + SZ_CT)                  // 512 doubles

// ---------------- K0: pack B/CT fragments, cnorm ----------------
__global__ __launch_bounds__(256) void ce_prep(
    const float* __restrict__ emb, const float* __restrict__ cent,
    u16* __restrict__ Bhi, u16* __restrict__ Blo,
    u16* __restrict__ CThi, u16* __restrict__ CTlo,
    double* __restrict__ cnormd)
{
  const int b = blockIdx.x, t = threadIdx.x;
  const int l = t & 63;
  const int lr = l & 15, lk = l >> 4;
  if (b < 1024) {                      // emb frag (nt 0..15, ksg 0..255): elem j = emb[ksg*32+lk*8+j][nt*16+lr]
    const int g  = b * 4 + (t >> 6);
    const int nt = g >> 8, ksg = g & 255;
    u32 hw[4], lw[4];
    #pragma unroll
    for (int p = 0; p < 4; ++p) {
      float va = emb[(size_t)(ksg*32 + lk*8 + 2*p    )*256 + nt*16 + lr];
      float vb = emb[(size_t)(ksg*32 + lk*8 + 2*p + 1)*256 + nt*16 + lr];
      split2(va, vb, hw[p], lw[p]);
    }
    const size_t fi = ((size_t)nt*256 + ksg)*64 + l;
    *(uint4*)(Bhi + fi*8) = make_uint4(hw[0],hw[1],hw[2],hw[3]);
    *(uint4*)(Blo + fi*8) = make_uint4(lw[0],lw[1],lw[2],lw[3]);
  } else if (b < 1088) {               // cent^T frags (nt 0..31, ksg 0..7), shifted by -0.5
    const int g  = (b - 1024) * 4 + (t >> 6);
    const int nt = g >> 3, ksg = g & 7;
    u32 hw[4], lw[4];
    #pragma unroll
    for (int p = 0; p < 4; ++p) {
      float va = cent[(size_t)(nt*16 + lr)*256 + ksg*32 + lk*8 + 2*p    ] - 0.5f;
      float vb = cent[(size_t)(nt*16 + lr)*256 + ksg*32 + lk*8 + 2*p + 1] - 0.5f;
      split2(va, vb, hw[p], lw[p]);
    }
    const size_t fi = ((size_t)nt*8 + ksg)*64 + l;
    *(uint4*)(CThi + fi*8) = make_uint4(hw[0],hw[1],hw[2],hw[3]);
    *(uint4*)(CTlo + fi*8) = make_uint4(lw[0],lw[1],lw[2],lw[3]);
  } else {                             // cnorm: |cent_k - 0.5|^2 in f64
    const int row = (b - 1088)*8 + (t >> 5);
    const int h = t & 31;
    double s = 0.0;
    #pragma unroll
    for (int j = 0; j < 8; ++j) {
      float x = cent[(size_t)row*256 + h*8 + j] - 0.5f;
      s += (double)x * (double)x;
    }
    #pragma unroll
    for (int off = 16; off > 0; off >>= 1) s += __shfl_xor(s, off);
    if (h == 0) cnormd[row] = s;
  }
}

// ---------------- K1: main split-bf16 GEMM, 512 WGs x 512 thr ----------------
// blk: mt = blk>>2 (row tile of 64), ks = blk&3 (K-quarter of 2048)
__global__ __launch_bounds__(512, 4) void ce_gemm(
    const float* __restrict__ seq,
    const u16* __restrict__ Bhi, const u16* __restrict__ Blo,
    float* __restrict__ part, float* __restrict__ cntpart)
{
  __shared__ char Ah[2][64*128];      // 64 rows x 64 bf16 (128B), slot-swizzled, dbuf
  __shared__ char Al[2][64*128];     // total LDS = 32 KB exactly

  const int t   = threadIdx.x;
  const int blk = blockIdx.x;
  const int mt  = blk >> 2;
  const int ks  = blk & 3;
  const size_t rowBase = (size_t)mt * 64;
  const int ar  = t >> 3;             // staging row 0..63 (fixed per thread -> count accum)
  const int ac  = t & 7;              // 8-float chunk
  const float* aptr = seq + (rowBase + ar) * 8192 + (size_t)ks * 2048 + ac * 8;

  const int w = t >> 6, l = t & 63;   // wave w owns cols w*32 .. w*32+31 (no B dup)
  const int lr = l & 15, lk = l >> 4;

  f32x4 acc[4][2];
  #pragma unroll
  for (int i = 0; i < 4; ++i)
    #pragma unroll
    for (int j = 0; j < 2; ++j) acc[i][j] = (f32x4){0.f,0.f,0.f,0.f};

  float csum = 0.f;
  float4 areg0, areg1;
  areg0 = *(const float4*)(aptr);
  areg1 = *(const float4*)(aptr + 4);

  // persistent ksub0 B-frag registers (prefetched one step ahead)
  bf16x8 bh0[2], bl0[2];
  {
    const int ksg0 = ks*64;
    #pragma unroll
    for (int ni = 0; ni < 2; ++ni) {
      const size_t fi = (((size_t)(w*2 + ni))*256 + ksg0)*64 + l;
      bh0[ni] = *(const bf16x8*)(Bhi + fi*8);
      bl0[ni] = *(const bf16x8*)(Blo + fi*8);
    }
  }

  // prologue: stage tile 0 into buf0, start loading tile 1
  {
    float v[8] = {areg0.x, areg0.y, areg0.z, areg0.w, areg1.x, areg1.y, areg1.z, areg1.w};
    #pragma unroll
    for (int i = 0; i < 8; ++i) csum += v[i];
    u32 hw[4], lw[4];
    #pragma unroll
    for (int p = 0; p < 4; ++p) split2(v[2*p], v[2*p+1], hw[p], lw[p]);
    const int off = ar*128 + ((ac ^ (ar & 7)) << 4);
    *(uint4*)(Ah[0] + off) = make_uint4(hw[0],hw[1],hw[2],hw[3]);
    *(uint4*)(Al[0] + off) = make_uint4(lw[0],lw[1],lw[2],lw[3]);
  }
  aptr += 64;
  areg0 = *(const float4*)(aptr);
  areg1 = *(const float4*)(aptr + 4);
  __syncthreads();

  for (int step = 0; step < 32; ++step) {
    const int cur = step & 1;
    const int ksg0 = ks*64 + step*2;
    // phase 1: issue ksub1 B loads (used after 24 MFMAs -> latency covered)
    bf16x8 bh1[2], bl1[2];
    #pragma unroll
    for (int ni = 0; ni < 2; ++ni) {
      const size_t fi = (((size_t)(w*2 + ni))*256 + (ksg0 + 1))*64 + l;
      bh1[ni] = *(const bf16x8*)(Bhi + fi*8);
      bl1[ni] = *(const bf16x8*)(Blo + fi*8);
    }
    // phase 2: stage NEXT tile into buf^1 (VALU; covers b1 latency)
    if (step < 31) {
      float v[8] = {areg0.x, areg0.y, areg0.z, areg0.w, areg1.x, areg1.y, areg1.z, areg1.w};
      #pragma unroll
      for (int i = 0; i < 8; ++i) csum += v[i];
      u32 hw[4], lw[4];
      #pragma unroll
      for (int p = 0; p < 4; ++p) split2(v[2*p], v[2*p+1], hw[p], lw[p]);
      const int off = ar*128 + ((ac ^ (ar & 7)) << 4);
      *(uint4*)(Ah[cur^1] + off) = make_uint4(hw[0],hw[1],hw[2],hw[3]);
      *(uint4*)(Al[cur^1] + off) = make_uint4(lw[0],lw[1],lw[2],lw[3]);
      if (step < 30) {
        aptr += 64;
        areg0 = *(const float4*)(aptr);
        areg1 = *(const float4*)(aptr + 4);
      }
    }
    // phase 3: ksub0 A frags + 24 MFMA with prefetched bh0/bl0
    {
      bf16x8 ah[4], alo[4];
      #pragma unroll
      for (int mi = 0; mi < 4; ++mi) {
        const int row = mi*16 + lr;
        const int off = row*128 + ((lk ^ (row & 7)) << 4);
        ah[mi]  = *(const bf16x8*)(Ah[cur] + off);
        alo[mi] = *(const bf16x8*)(Al[cur] + off);
      }
      #pragma unroll
      for (int mi = 0; mi < 4; ++mi)
        #pragma unroll
        for (int ni = 0; ni < 2; ++ni) {
          acc[mi][ni] = MFMA_B16(ah[mi],  bh0[ni], acc[mi][ni]);
          acc[mi][ni] = MFMA_B16(alo[mi], bh0[ni], acc[mi][ni]);
          acc[mi][ni] = MFMA_B16(ah[mi],  bl0[ni], acc[mi][ni]);
        }
    }
    // phase 4: prefetch ksub0 B for NEXT step (latency covered by phase-5 MFMAs)
    if (step < 31) {
      const int nksg0 = ksg0 + 2;
      #pragma unroll
      for (int ni = 0; ni < 2; ++ni) {
        const size_t fi = (((size_t)(w*2 + ni))*256 + nksg0)*64 + l;
        bh0[ni] = *(const bf16x8*)(Bhi + fi*8);
        bl0[ni] = *(const bf16x8*)(Blo + fi*8);
      }
    }
    // phase 5: ksub1 A frags + 24 MFMA with bh1/bl1
    {
      bf16x8 ah[4], alo[4];
      #pragma unroll
      for (int mi = 0; mi < 4; ++mi) {
        const int row = mi*16 + lr;
        const int off = row*128 + (((4 + lk) ^ (row & 7)) << 4);
        ah[mi]  = *(const bf16x8*)(Ah[cur] + off);
        alo[mi] = *(const bf16x8*)(Al[cur] + off);
      }
      #pragma unroll
      for (int mi = 0; mi < 4; ++mi)
        #pragma unroll
        for (int ni = 0; ni < 2; ++ni) {
          acc[mi][ni] = MFMA_B16(ah[mi],  bh1[ni], acc[mi][ni]);
          acc[mi][ni] = MFMA_B16(alo[mi], bh1[ni], acc[mi][ni]);
          acc[mi][ni] = MFMA_B16(ah[mi],  bl1[ni], acc[mi][ni]);
        }
    }
    __syncthreads();
  }
  // count partials: 8 lanes (same ar) shuffle-reduce, lane ac==0 writes
  {
    float c = csum;
    c += __shfl_xor(c, 1);
    c += __shfl_xor(c, 2);
    c += __shfl_xor(c, 4);
    if (ac == 0) cntpart[(size_t)ks*8192 + rowBase + ar] = c;
  }
  // partial e_free store (C/D layout: col = l&15, row = (l>>4)*4 + reg)
  float* pbase = part + ((size_t)ks*8192 + rowBase)*256;
  #pragma unroll
  for (int mi = 0; mi < 4; ++mi)
    #pragma unroll
    for (int ni = 0; ni < 2; ++ni) {
      const int col = w*32 + ni*16 + lr;
      #pragma unroll
      for (int rr = 0; rr < 4; ++rr) {
        const int row = mi*16 + lk*4 + rr;
        pbase[(size_t)row*256 + col] = acc[mi][ni][rr];
      }
    }
}

// ---------------- K2: reduce + centroid argmin + blend, 256 WGs x 256 thr ----------------
__global__ __launch_bounds__(256) void ce_cent(
    const float* __restrict__ part, const float* __restrict__ cntpart,
    const u16* __restrict__ CThi, const u16* __restrict__ CTlo,
    const double* __restrict__ cnormd, const float* __restrict__ cent,
    float* __restrict__ out)
{
  __shared__ float eL[32][256];       // e_free rows (f32)
  __shared__ char Eh[32*512];         // shifted e hi bf16, swizzled [row][256]
  __shared__ char El[32*512];
  __shared__ float GL[32][512];       // (e-.5)·(c-.5)^T
  __shared__ float cntL[32];
  __shared__ float enred[32][8];
  __shared__ float enL[32];

  const int t = threadIdx.x;
  const size_t rb = (size_t)blockIdx.x * 32;
  const int r  = t >> 3;
  const int c0 = (t & 7) * 32;

  if (t < 32) {
    float s = 0.f;
    #pragma unroll
    for (int p = 0; p < NSPLIT; ++p) s += cntpart[(size_t)p*8192 + rb + t];
    cntL[t] = (s == 0.f) ? 1.f : s;
  }
  __syncthreads();
  const float inv = 1.0f / cntL[r];
  float en = 0.f;
  #pragma unroll
  for (int jp = 0; jp < 4; ++jp) {    // 8 cols per iter
    float e8[8];
    #pragma unroll
    for (int q = 0; q < 2; ++q) {
      const float* p0 = part + (rb + r)*256 + c0 + jp*8 + q*4;
      float4 e4 = {0.f, 0.f, 0.f, 0.f};
      #pragma unroll
      for (int p = 0; p < NSPLIT; ++p) {
        float4 s0 = *(const float4*)(p0 + (size_t)p*2097152);
        e4.x += s0.x; e4.y += s0.y; e4.z += s0.z; e4.w += s0.w;
      }
      e4.x *= inv; e4.y *= inv; e4.z *= inv; e4.w *= inv;
      *(float4*)&eL[r][c0 + jp*8 + q*4] = e4;
      e8[q*4+0] = e4.x; e8[q*4+1] = e4.y; e8[q*4+2] = e4.z; e8[q*4+3] = e4.w;
    }
    u32 hw[4], lw[4];
    #pragma unroll
    for (int p = 0; p < 4; ++p) {
      float va = e8[2*p] - 0.5f, vb = e8[2*p+1] - 0.5f;
      split2(va, vb, hw[p], lw[p]);
      en += va*va + vb*vb;
    }
    const int slot = (t & 7)*4 + jp;                 // 0..31
    const int off  = r*512 + ((slot ^ (r & 7)) << 4);
    *(uint4*)(Eh + off) = make_uint4(hw[0],hw[1],hw[2],hw[3]);
    *(uint4*)(El + off) = make_uint4(lw[0],lw[1],lw[2],lw[3]);
  }
  enred[r][t & 7] = en;
  __syncthreads();
  if (t < 32) {
    float s = 0.f;
    #pragma unroll
    for (int j = 0; j < 8; ++j) s += enred[t][j];
    enL[t] = s;
  }
  // G = Ẽ · C̃^T via 3-pass split MFMA; wave w owns 128 centroids
  const int w = t >> 6, l = t & 63, lr = l & 15, lk = l >> 4;
  f32x4 acc[2][8];
  #pragma unroll
  for (int i = 0; i < 2; ++i)
    #pragma unroll
    for (int j = 0; j < 8; ++j) acc[i][j] = (f32x4){0.f,0.f,0.f,0.f};
  #pragma unroll
  for (int ksub = 0; ksub < 8; ++ksub) {
    bf16x8 ah[2], alo[2];
    #pragma unroll
    for (int mi = 0; mi < 2; ++mi) {
      const int row = mi*16 + lr;
      const int off = row*512 + (((ksub*4 + lk) ^ (row & 7)) << 4);
      ah[mi]  = *(const bf16x8*)(Eh + off);
      alo[mi] = *(const bf16x8*)(El + off);
    }
    bf16x8 bh[8], bl[8];
    #pragma unroll
    for (int ni = 0; ni < 8; ++ni) {
      const size_t fi = (((size_t)(w*8 + ni))*8 + ksub)*64 + l;
      bh[ni] = *(const bf16x8*)(CThi + fi*8);
      bl[ni] = *(const bf16x8*)(CTlo + fi*8);
    }
    #pragma unroll
    for (int mi = 0; mi < 2; ++mi)
      #pragma unroll
      for (int ni = 0; ni < 8; ++ni) {
        acc[mi][ni] = MFMA_B16(ah[mi],  bh[ni], acc[mi][ni]);
        acc[mi][ni] = MFMA_B16(alo[mi], bh[ni], acc[mi][ni]);
        acc[mi][ni] = MFMA_B16(ah[mi],  bl[ni], acc[mi][ni]);
      }
  }
  #pragma unroll
  for (int mi = 0; mi < 2; ++mi)
    #pragma unroll
    for (int ni = 0; ni < 8; ++ni)
      #pragma unroll
      for (int rr = 0; rr < 4; ++rr)
        GL[mi*16 + lk*4 + rr][w*128 + ni*16 + lr] = acc[mi][ni][rr];
  __syncthreads();
  // argmin (f64 combine; exact first-index tie-break) + blend + store; wave w rows w*8..w*8+7
  for (int i = 0; i < 8; ++i) {
    const int row = w*8 + i;
    const double en_ = (double)enL[row];
    double best = 1e300; int bk = 0;
    #pragma unroll
    for (int jj = 0; jj < 8; ++jj) {
      const int k = jj*64 + l;
      const double d2 = en_ + cnormd[k] - 2.0*(double)GL[row][k];
      if (d2 < best) { best = d2; bk = k; }
    }
    #pragma unroll
    for (int off = 32; off > 0; off >>= 1) {
      const double ov = __shfl_xor(best, off);
      const int   ok = __shfl_xor(bk, off);
      if (ov < best || (ov == best && ok < bk)) { best = ov; bk = ok; }
    }
    const float* crow = cent + (size_t)bk*256;
    float4 ef = *(const float4*)&eL[row][l*4];
    float4 cf = *(const float4*)(crow + l*4);
    float4 o;
    o.x = 0.1f*ef.x + 0.9f*cf.x;
    o.y = 0.1f*ef.y + 0.9f*cf.y;
    o.z = 0.1f*ef.z + 0.9f*cf.z;
    o.w = 0.1f*ef.w + 0.9f*cf.w;
    *(float4*)(out + (rb + row)*256 + l*4) = o;
  }
}

extern "C" void kernel_launch(void* const* d_in, const int* in_sizes, int n_in,
                              void* d_out, int out_size, void* d_ws, size_t ws_size,
                              hipStream_t stream) {
  const float* seq  = (const float*)d_in[0];
  const float* emb  = (const float*)d_in[1];
  const float* cent = (const float*)d_in[2];
  float* out = (float*)d_out;
  char* ws = (char*)d_ws;

  float*  part    = (float*) (ws);
  float*  cntpart = (float*) (ws + OFF_CNT);
  u16*    Bhi     = (u16*)   (ws + OFF_BHI);
  u16*    Blo     = (u16*)   (ws + OFF_BLO);
  u16*    CThi    = (u16*)   (ws + OFF_CTHI);
  u16*    CTlo    = (u16*)   (ws + OFF_CTLO);
  double* cnormd  = (double*)(ws + OFF_CNORM);

  hipLaunchKernelGGL(ce_prep, dim3(1152), dim3(256), 0, stream,
                     emb, cent, Bhi, Blo, CThi, CTlo, cnormd);
  hipLaunchKernelGGL(ce_gemm, dim3(512), dim3(512), 0, stream,
                     seq, Bhi, Blo, part, cntpart);
  hipLaunchKernelGGL(ce_cent, dim3(256), dim3(256), 0, stream,
                     part, cntpart, CThi, CTlo, cnormd, cent, out);
}